// Round 6
// baseline (617.534 us; speedup 1.0000x reference)
//
#include <hip/hip_runtime.h>
#include <hip/hip_fp16.h>
#include <cstdint>
#include <cstddef>

#define N_NODES 50000
#define N_EDGES 800000
#define F_IN 128
#define H_HEADS 4
#define C1 64
#define C2 32
#define NEG_SLOPE 0.2f
#define EPS_GAT 1e-16f

typedef _Float16 half8 __attribute__((ext_vector_type(8)));
typedef float f32x4 __attribute__((ext_vector_type(4)));

// ---------------------------------------------------------------------------
// W pre-transpose: Wt[m][k] = (f16)W[k][m].  K, M multiples of 64.
// ---------------------------------------------------------------------------
template<int K, int M>
__global__ __launch_bounds__(256) void wtrans_kernel(const float* __restrict__ W,
                                                     _Float16* __restrict__ Wt) {
    __shared__ _Float16 tile[64 * 66];
    const int m0 = blockIdx.x * 64, k0 = blockIdx.y * 64;
    const int t = threadIdx.x;
    const int c = t & 63;
#pragma unroll
    for (int j = 0; j < 16; ++j) {
        int r = (t >> 6) + 4 * j;                 // k-local
        tile[c * 66 + r] = (_Float16)W[(size_t)(k0 + r) * M + m0 + c];
    }
    __syncthreads();
#pragma unroll
    for (int j = 0; j < 16; ++j) {
        int m_l = (t >> 6) + 4 * j;
        Wt[(size_t)(m0 + m_l) * K + k0 + c] = tile[m_l * 66 + c];
    }
}

// ---------------------------------------------------------------------------
// Fused GEMM + attention-dot kernel (unchanged from R4/R5 structure).
// h = X @ W (Wt pre-transposed f16), h stored f16;
// as_/ad_[n,h] += sum_c h[n,h,c]*att{s,d}[h,c] (fp32 acc, atomicAdd).
// ---------------------------------------------------------------------------
template<int K, int M, int Hn, int C, typename InT>
__global__ __launch_bounds__(256) void gemm_att_kernel(
        const InT* __restrict__ X, const _Float16* __restrict__ Wt,
        _Float16* __restrict__ Hout,
        const float* __restrict__ atts, const float* __restrict__ attd,
        float* __restrict__ as_, float* __restrict__ ad_, int Nr) {
    constexpr int LDK = K + 8;
    constexpr int HPB = 64 / C;
    __shared__ _Float16 Ah[64 * LDK];
    __shared__ _Float16 Bt[64 * LDK];
    const int row0 = blockIdx.x * 64;
    const int col0 = blockIdx.y * 64;
    const int t = threadIdx.x;
    const int wv = t >> 6;
    const int lane = t & 63;
    const int quad = lane >> 4;
    const int n16 = lane & 15;

    if constexpr (sizeof(InT) == 4) {
        constexpr int KQ = K / 4;
#pragma unroll
        for (int j = 0; j < (64 * KQ) / 256; ++j) {
            int flat = t + 256 * j;
            int r = flat / KQ, kq = flat % KQ;
            int rg = row0 + r;
            float4 v = make_float4(0.f, 0.f, 0.f, 0.f);
            if (rg < Nr) v = *(const float4*)&X[(size_t)rg * K + 4 * kq];
            _Float16 tmp[4] = {(_Float16)v.x, (_Float16)v.y, (_Float16)v.z, (_Float16)v.w};
            *(uint2*)&Ah[r * LDK + 4 * kq] = *(const uint2*)tmp;
        }
    } else {
        constexpr int KQ = K / 8;
#pragma unroll
        for (int j = 0; j < (64 * KQ) / 256; ++j) {
            int flat = t + 256 * j;
            int r = flat / KQ, kq = flat % KQ;
            int rg = row0 + r;
            uint4 v = make_uint4(0u, 0u, 0u, 0u);
            if (rg < Nr) v = *(const uint4*)&X[(size_t)rg * K + 8 * kq];
            *(uint4*)&Ah[r * LDK + 8 * kq] = v;
        }
    }
    {
        constexpr int KQ8 = K / 8;
#pragma unroll
        for (int j = 0; j < (64 * KQ8) / 256; ++j) {
            int flat = t + 256 * j;
            int c = flat / KQ8, kq = flat % KQ8;
            uint4 v = *(const uint4*)&Wt[(size_t)(col0 + c) * K + 8 * kq];
            *(uint4*)&Bt[c * LDK + 8 * kq] = v;
        }
    }
    __syncthreads();

    f32x4 acc[4];
#pragma unroll
    for (int nf = 0; nf < 4; ++nf) acc[nf] = (f32x4){0.f, 0.f, 0.f, 0.f};
    const _Float16* Ap = &Ah[(16 * wv + n16) * LDK + 8 * quad];
#pragma unroll
    for (int ki = 0; ki < K / 32; ++ki) {
        half8 af = *(const half8*)(Ap + 32 * ki);
#pragma unroll
        for (int nf = 0; nf < 4; ++nf) {
            half8 bf = *(const half8*)&Bt[(16 * nf + n16) * LDK + 32 * ki + 8 * quad];
            acc[nf] = __builtin_amdgcn_mfma_f32_16x16x32_f16(af, bf, acc[nf], 0, 0, 0);
        }
    }

    // attention partial dots (C/D layout: col=lane&15, row=quad*4+r)
    float dps[HPB][4], dpd[HPB][4];
#pragma unroll
    for (int u = 0; u < HPB; ++u)
#pragma unroll
        for (int r = 0; r < 4; ++r) { dps[u][r] = 0.f; dpd[u][r] = 0.f; }
#pragma unroll
    for (int nf = 0; nf < 4; ++nf) {
        int gc = col0 + 16 * nf + n16;
        float cs = atts[gc], cd = attd[gc];
#pragma unroll
        for (int r = 0; r < 4; ++r) {
            float av = acc[nf][r];
            dps[(16 * nf) / C][r] += av * cs;
            dpd[(16 * nf) / C][r] += av * cd;
        }
    }
#pragma unroll
    for (int u = 0; u < HPB; ++u)
#pragma unroll
        for (int r = 0; r < 4; ++r) {
            float s = dps[u][r], d = dpd[u][r];
#pragma unroll
            for (int off = 1; off < 16; off <<= 1) {
                s += __shfl_xor(s, off, 64);
                d += __shfl_xor(d, off, 64);
            }
            dps[u][r] = s; dpd[u][r] = d;
        }
    if (n16 == 0) {
        const int h0 = col0 / C;
#pragma unroll
        for (int r = 0; r < 4; ++r) {
            int row = row0 + 16 * wv + 4 * quad + r;
            if (row < Nr) {
#pragma unroll
                for (int u = 0; u < HPB; ++u) {
                    atomicAdd(&as_[row * Hn + h0 + u], dps[u][r]);
                    atomicAdd(&ad_[row * Hn + h0 + u], dpd[u][r]);
                }
            }
        }
    }

    // store h tile via LDS bounce (stride 72) for dwordx4 stores
    __syncthreads();
    _Float16* Ht = Ah;
#pragma unroll
    for (int nf = 0; nf < 4; ++nf)
#pragma unroll
        for (int r = 0; r < 4; ++r)
            Ht[(16 * wv + 4 * quad + r) * 72 + 16 * nf + n16] = (_Float16)acc[nf][r];
    __syncthreads();
#pragma unroll
    for (int j = 0; j < 2; ++j) {
        int chunk = t + 256 * j;
        int r = chunk >> 3, cc = chunk & 7;
        int row = row0 + r;
        if (row < Nr) {
            uint4 v = *(const uint4*)&Ht[r * 72 + 8 * cc];
            *(uint4*)&Hout[(size_t)row * M + col0 + 8 * cc] = v;
        }
    }
}

// ---------------------------------------------------------------------------
// CSR build: histogram -> 3-stage scan -> scatter.
// ---------------------------------------------------------------------------
__global__ __launch_bounds__(256) void count_kernel(const int* __restrict__ dst,
                                                    int* __restrict__ deg, int Ecnt) {
    int e = blockIdx.x * 256 + threadIdx.x;
    if (e < Ecnt) atomicAdd(&deg[dst[e]], 1);
}

__global__ __launch_bounds__(256) void scan_partial(const int* __restrict__ deg,
                                                    int* __restrict__ bsum, int n) {
    int i = blockIdx.x * 256 + threadIdx.x;
    int v = (i < n) ? deg[i] : 0;
    int lane = threadIdx.x & 63, wv = threadIdx.x >> 6;
#pragma unroll
    for (int off = 32; off > 0; off >>= 1) v += __shfl_down(v, off, 64);
    __shared__ int wt[4];
    if (lane == 0) wt[wv] = v;
    __syncthreads();
    if (threadIdx.x == 0) bsum[blockIdx.x] = wt[0] + wt[1] + wt[2] + wt[3];
}

__global__ __launch_bounds__(256) void scan_base(int* __restrict__ bsum, int nb,
                                                 int* __restrict__ total_out) {
    int t = threadIdx.x, lane = t & 63, wv = t >> 6;
    int v = (t < nb) ? bsum[t] : 0;
    int x = v;
#pragma unroll
    for (int off = 1; off < 64; off <<= 1) {
        int y = __shfl_up(x, off, 64);
        if (lane >= off) x += y;
    }
    __shared__ int wt[4];
    if (lane == 63) wt[wv] = x;
    __syncthreads();
    int base = 0;
    for (int k = 0; k < wv; ++k) base += wt[k];
    if (t < nb) bsum[t] = base + x - v;
    if (t == 255) *total_out = base + x;
}

__global__ __launch_bounds__(256) void scan_final(const int* __restrict__ deg,
                                                  const int* __restrict__ bsum,
                                                  int* __restrict__ row_off,
                                                  int* __restrict__ cursor, int n) {
    int i = blockIdx.x * 256 + threadIdx.x;
    int t = threadIdx.x, lane = t & 63, wv = t >> 6;
    int v = (i < n) ? deg[i] : 0;
    int x = v;
#pragma unroll
    for (int off = 1; off < 64; off <<= 1) {
        int y = __shfl_up(x, off, 64);
        if (lane >= off) x += y;
    }
    __shared__ int wt[4];
    if (lane == 63) wt[wv] = x;
    __syncthreads();
    int base = bsum[blockIdx.x];
    for (int k = 0; k < wv; ++k) base += wt[k];
    int ro = base + x - v;
    if (i < n) { row_off[i] = ro; cursor[i] = ro; }
}

__global__ __launch_bounds__(256) void scatter_kernel(const int* __restrict__ src,
                                                      const int* __restrict__ dst,
                                                      int* __restrict__ cursor,
                                                      int* __restrict__ ssrc, int Ecnt) {
    int e = blockIdx.x * 256 + threadIdx.x;
    if (e >= Ecnt) return;
    int p = atomicAdd(&cursor[dst[e]], 1);
    ssrc[p] = src[e];
}

// ---------------------------------------------------------------------------
// XCD-chunked GAT aggregation.
// The h columns are split into 8 chunks of CW=HC/8 f16 (one half-head).
// chunk = blockIdx.x % 8 -> round-robin dispatch pins each chunk to one XCD,
// whose 4 MB L2 holds the chunk's h slice (3.2 MB L1 / 1.6 MB L2-layer) ->
// the random edge gather becomes L2-hits instead of L2 fills.
// Each chunk writes its attended per-head slice:
//   partial[chunk][n][CW] = (Σ_e w_e h[src_e, cols]) / (Σ_e w_e + eps)
// Per wave: EPW=64/LPE edges in parallel (LPE lanes/edge, 16 B each);
// grid-stride over nodes.
// ---------------------------------------------------------------------------
template<int Hn, int C>
__global__ __launch_bounds__(256) void chunk_agg_kernel(
        const int* __restrict__ row_off, const int* __restrict__ ssrc,
        const float* __restrict__ as_, const float* __restrict__ ad_,
        const _Float16* __restrict__ Hm, float* __restrict__ partial,
        int Nr, int ngrp) {
    constexpr int HC = Hn * C;
    constexpr int CW = HC / 8;       // 32 (L1) / 16 (L2) f16 per chunk-row
    constexpr int LPE = CW / 8;      // lanes per edge: 4 / 2
    constexpr int EPW = 64 / LPE;    // edges per wave-iteration: 16 / 32
    const int chunk = blockIdx.x & 7;
    const int grp = blockIdx.x >> 3;
    const int wv = threadIdx.x >> 6;
    const int lane = threadIdx.x & 63;
    const int eg = lane / LPE;       // edge group
    const int li = lane % LPE;       // lane within edge
    const int head = chunk >> 1;     // CW = C/2 in both layers
    const int colbase = chunk * CW;
    const int strideN = ngrp * 4;
    float* pbase = partial + (size_t)chunk * Nr * CW;

    for (int node = grp * 4 + wv; node < Nr; node += strideN) {
        const float ad_h = ad_[node * Hn + head];
        const int begin = row_off[node], end = row_off[node + 1];
        float acc[8];
#pragma unroll
        for (int t = 0; t < 8; ++t) acc[t] = 0.f;
        float wsum = 0.f;
        if (begin < end) {
            const int endc = end - 1;
            const int iters = (end - begin + EPW - 1) / EPW;
            int idx = begin + eg;
            for (int it = 0; it < iters; ++it) {
                int ic = min(idx, endc);             // clamped, always valid
                int s = ssrc[ic];
                float a = as_[s * Hn + head];
                float logit = a + ad_h;
                logit = (logit > 0.f) ? logit : NEG_SLOPE * logit;
                float w = (idx <= endc) ? __expf(logit) : 0.f;
                wsum += w;
                half8 u = *(const half8*)(Hm + (size_t)s * HC + colbase + li * 8);
#pragma unroll
                for (int t = 0; t < 8; ++t)
                    acc[t] += w * (float)u[t];       // v_fma_mix_f32
                idx += EPW;
            }
        }
        // reduce across edge groups (xor bits >= log2(LPE))
#pragma unroll
        for (int off = LPE; off < 64; off <<= 1) {
#pragma unroll
            for (int t = 0; t < 8; ++t) acc[t] += __shfl_xor(acc[t], off, 64);
            wsum += __shfl_xor(wsum, off, 64);
        }
        const float inv = 1.f / (wsum + EPS_GAT);    // zero-degree: 0
        if (eg == 0) {                                // lanes 0..LPE-1
            float* pp = pbase + (size_t)node * CW + li * 8;
            *(float4*)pp = make_float4(acc[0] * inv, acc[1] * inv, acc[2] * inv, acc[3] * inv);
            *(float4*)(pp + 4) = make_float4(acc[4] * inv, acc[5] * inv, acc[6] * inv, acc[7] * inv);
        }
    }
}

// ---------------------------------------------------------------------------
// Combine: out[n,c] = act( mean_h partial[(h, c/CW)][n][c%CW] + bias[c] )
// ---------------------------------------------------------------------------
template<int Hn, int C, bool RELU, bool OUT_F16>
__global__ __launch_bounds__(256) void combine_kernel(
        const float* __restrict__ partial, const float* __restrict__ bias,
        void* __restrict__ outv, int Nr) {
    constexpr int CW = Hn * C / 8;
    int idx = blockIdx.x * 256 + threadIdx.x;
    if (idx >= Nr * C) return;
    int n = idx / C, c = idx % C;
    int half = c / CW, sub = c % CW;
    float v = 0.f;
#pragma unroll
    for (int h = 0; h < Hn; ++h)
        v += partial[((size_t)(2 * h + half) * Nr + n) * CW + sub];
    v = v * (1.0f / Hn) + bias[c];
    if (RELU) v = fmaxf(v, 0.f);
    if constexpr (OUT_F16) ((_Float16*)outv)[idx] = (_Float16)v;
    else                   ((float*)outv)[idx] = v;
}

// ---------------------------------------------------------------------------
extern "C" void kernel_launch(void* const* d_in, const int* in_sizes, int n_in,
                              void* d_out, int out_size, void* d_ws, size_t ws_size,
                              hipStream_t stream) {
    const float* x    = (const float*)d_in[0];
    const int*   ei   = (const int*)d_in[1];
    const float* W1   = (const float*)d_in[2];
    const float* as1w = (const float*)d_in[3];
    const float* ad1w = (const float*)d_in[4];
    const float* b1   = (const float*)d_in[5];
    const float* W2   = (const float*)d_in[6];
    const float* as2w = (const float*)d_in[7];
    const float* ad2w = (const float*)d_in[8];
    const float* b2   = (const float*)d_in[9];
    float* out = (float*)d_out;

    const int* src = ei;             // edge_index[0]
    const int* dst = ei + N_EDGES;   // edge_index[1]

    char* ws = (char*)d_ws;
    size_t off = 0;
    auto alloc = [&](size_t bytes) -> void* {
        void* p = ws + off;
        off = (off + bytes + 255) & ~(size_t)255;
        return p;
    };
    const int NB = (N_NODES + 255) / 256;   // 196 scan blocks
    // one contiguous zero region: deg | as1 | ad1 | as2 | ad2
    int*   deg  = (int*)alloc((size_t)N_NODES * 4);
    float* as1_ = (float*)alloc((size_t)N_NODES * H_HEADS * 4);
    float* ad1_ = (float*)alloc((size_t)N_NODES * H_HEADS * 4);
    float* as2_ = (float*)alloc((size_t)N_NODES * H_HEADS * 4);
    float* ad2_ = (float*)alloc((size_t)N_NODES * H_HEADS * 4);
    const size_t zero_span = (char*)(ad2_ + (size_t)N_NODES * H_HEADS) - (char*)deg;

    _Float16* h1   = (_Float16*)alloc((size_t)N_NODES * H_HEADS * C1 * 2);  // 25.6 MB
    _Float16* out1 = (_Float16*)alloc((size_t)N_NODES * C1 * 2);            // 6.4 MB
    _Float16* h2   = (_Float16*)alloc((size_t)N_NODES * H_HEADS * C2 * 2);  // 12.8 MB
    _Float16* wt1  = (_Float16*)alloc((size_t)(H_HEADS * C1) * F_IN * 2);   // 64 KB
    _Float16* wt2  = (_Float16*)alloc((size_t)(H_HEADS * C2) * C1 * 2);     // 16 KB
    int*   row_off = (int*)alloc((size_t)(N_NODES + 1) * 4);
    int*   cursor  = (int*)alloc((size_t)N_NODES * 4);
    int*   ssrc    = (int*)alloc((size_t)N_EDGES * 4);
    int*   bsum    = (int*)alloc((size_t)NB * 4);
    float* partial = (float*)alloc((size_t)8 * N_NODES * (H_HEADS * C1 / 8) * 4);  // 51.2 MB (reused for layer 2)

    // ---- zero + W transposes + CSR build ----
    hipMemsetAsync(deg, 0, zero_span, stream);
    wtrans_kernel<F_IN, H_HEADS * C1><<<dim3((H_HEADS * C1) / 64, F_IN / 64), 256, 0, stream>>>(W1, wt1);
    wtrans_kernel<C1, H_HEADS * C2><<<dim3((H_HEADS * C2) / 64, C1 / 64), 256, 0, stream>>>(W2, wt2);
    count_kernel<<<(N_EDGES + 255) / 256, 256, 0, stream>>>(dst, deg, N_EDGES);
    scan_partial<<<NB, 256, 0, stream>>>(deg, bsum, N_NODES);
    scan_base<<<1, 256, 0, stream>>>(bsum, NB, &row_off[N_NODES]);
    scan_final<<<NB, 256, 0, stream>>>(deg, bsum, row_off, cursor, N_NODES);
    scatter_kernel<<<(N_EDGES + 255) / 256, 256, 0, stream>>>(src, dst, cursor, ssrc, N_EDGES);

    const int NGRP = 784;            // chunk-agg node groups; grid = 8*NGRP

    // ---- layer 1 ----
    gemm_att_kernel<F_IN, H_HEADS * C1, H_HEADS, C1, float>
        <<<dim3((N_NODES + 63) / 64, (H_HEADS * C1) / 64), 256, 0, stream>>>(
            x, wt1, h1, as1w, ad1w, as1_, ad1_, N_NODES);
    chunk_agg_kernel<H_HEADS, C1><<<8 * NGRP, 256, 0, stream>>>(
        row_off, ssrc, as1_, ad1_, h1, partial, N_NODES, NGRP);
    combine_kernel<H_HEADS, C1, true, true><<<(N_NODES * C1 + 255) / 256, 256, 0, stream>>>(
        partial, b1, (void*)out1, N_NODES);

    // ---- layer 2 ----
    gemm_att_kernel<C1, H_HEADS * C2, H_HEADS, C2, _Float16>
        <<<dim3((N_NODES + 63) / 64, (H_HEADS * C2) / 64), 256, 0, stream>>>(
            out1, wt2, h2, as2w, ad2w, as2_, ad2_, N_NODES);
    chunk_agg_kernel<H_HEADS, C2><<<8 * NGRP, 256, 0, stream>>>(
        row_off, ssrc, as2_, ad2_, h2, partial, N_NODES, NGRP);
    combine_kernel<H_HEADS, C2, false, false><<<(N_NODES * C2 + 255) / 256, 256, 0, stream>>>(
        partial, b2, (void*)out, N_NODES);
}

// Round 7
// 294.545 us; speedup vs baseline: 2.0966x; 2.0966x over previous
//
#include <hip/hip_runtime.h>
#include <hip/hip_fp16.h>
#include <cstdint>
#include <cstddef>

#define N_NODES 50000
#define N_EDGES 800000
#define F_IN 128
#define H_HEADS 4
#define C1 64
#define C2 32
#define NEG_SLOPE 0.2f
#define EPS_GAT 1e-16f

typedef _Float16 half8 __attribute__((ext_vector_type(8)));
typedef float f32x4 __attribute__((ext_vector_type(4)));

// ---------------------------------------------------------------------------
// W pre-transpose device helper + fused kernel (both layers in one launch).
// Wt[m][k] = (f16)W[k][m]
// ---------------------------------------------------------------------------
template<int K, int M>
__device__ __forceinline__ void wtrans_dev(const float* __restrict__ W,
                                           _Float16* __restrict__ Wt,
                                           _Float16* tile, int bm, int bk) {
    const int m0 = bm * 64, k0 = bk * 64;
    const int t = threadIdx.x;
    const int c = t & 63;
#pragma unroll
    for (int j = 0; j < 16; ++j) {
        int r = (t >> 6) + 4 * j;                 // k-local
        tile[c * 66 + r] = (_Float16)W[(size_t)(k0 + r) * M + m0 + c];
    }
    __syncthreads();
#pragma unroll
    for (int j = 0; j < 16; ++j) {
        int m_l = (t >> 6) + 4 * j;
        Wt[(size_t)(m0 + m_l) * K + k0 + c] = tile[m_l * 66 + c];
    }
}

__global__ __launch_bounds__(256) void wtrans_both_kernel(
        const float* __restrict__ W1, _Float16* __restrict__ wt1,
        const float* __restrict__ W2, _Float16* __restrict__ wt2) {
    __shared__ _Float16 tile[64 * 66];
    int b = blockIdx.x;
    if (b < 8) {   // layer 1: M=256 (4 m-tiles), K=128 (2 k-tiles)
        wtrans_dev<F_IN, H_HEADS * C1>(W1, wt1, tile, b & 3, b >> 2);
    } else {       // layer 2: M=128 (2 m-tiles), K=64 (1 k-tile)
        wtrans_dev<C1, H_HEADS * C2>(W2, wt2, tile, b - 8, 0);
    }
}

// ---------------------------------------------------------------------------
// Fused GEMM + attention-dot kernel, full-M tile per block.
// h = X @ W (Wt pre-transposed f16), h stored f16.
// One block = 64 rows x ALL M cols (loop over 64-col tiles; A staged once,
// af frags cached in registers). Since a block sees all heads for its rows,
// as_/ad_[n,h] = sum_c h[n,h,c]*att{s,d}[h,c] are PLAIN stores (no atomics).
// MFMA 16x16x32 f16; C/D layout: col=lane&15, row=quad*4+r.
// ---------------------------------------------------------------------------
template<int K, int M, int Hn, int C, typename InT>
__global__ __launch_bounds__(256) void gemm_att_kernel(
        const InT* __restrict__ X, const _Float16* __restrict__ Wt,
        _Float16* __restrict__ Hout,
        const float* __restrict__ atts, const float* __restrict__ attd,
        float* __restrict__ as_, float* __restrict__ ad_, int Nr) {
    constexpr int LDK = K + 8;        // halves; row stride 2*LDK B = 16B multiple
    constexpr int NCT = M / 64;       // col tiles
    constexpr int HPB = 64 / C;       // heads per col tile (1 or 2)
    __shared__ _Float16 Ah[64 * LDK];
    __shared__ _Float16 Bt[64 * LDK];
    __shared__ _Float16 Ht[64 * 72];
    const int row0 = blockIdx.x * 64;
    const int t = threadIdx.x;
    const int wv = t >> 6;
    const int lane = t & 63;
    const int quad = lane >> 4;
    const int n16 = lane & 15;

    // ---- stage A once ----
    if constexpr (sizeof(InT) == 4) {           // f32 input: cast in flight
        constexpr int KQ = K / 4;
#pragma unroll
        for (int j = 0; j < (64 * KQ) / 256; ++j) {
            int flat = t + 256 * j;
            int r = flat / KQ, kq = flat % KQ;
            int rg = row0 + r;
            float4 v = make_float4(0.f, 0.f, 0.f, 0.f);
            if (rg < Nr) v = *(const float4*)&X[(size_t)rg * K + 4 * kq];
            _Float16 tmp[4] = {(_Float16)v.x, (_Float16)v.y, (_Float16)v.z, (_Float16)v.w};
            *(uint2*)&Ah[r * LDK + 4 * kq] = *(const uint2*)tmp;
        }
    } else {                                    // f16 input: straight copy
        constexpr int KQ = K / 8;
#pragma unroll
        for (int j = 0; j < (64 * KQ) / 256; ++j) {
            int flat = t + 256 * j;
            int r = flat / KQ, kq = flat % KQ;
            int rg = row0 + r;
            uint4 v = make_uint4(0u, 0u, 0u, 0u);
            if (rg < Nr) v = *(const uint4*)&X[(size_t)rg * K + 8 * kq];
            *(uint4*)&Ah[r * LDK + 8 * kq] = v;
        }
    }
    __syncthreads();

    // cache this wave's A fragments across all col tiles
    half8 af[K / 32];
    const _Float16* Ap = &Ah[(16 * wv + n16) * LDK + 8 * quad];
#pragma unroll
    for (int ki = 0; ki < K / 32; ++ki) af[ki] = *(const half8*)(Ap + 32 * ki);

    for (int ct = 0; ct < NCT; ++ct) {
        const int col0 = 64 * ct;
        __syncthreads();              // prior tile's Bt/Ht reads complete
        // ---- stage Bt for this col tile ----
        {
            constexpr int KQ8 = K / 8;
#pragma unroll
            for (int j = 0; j < (64 * KQ8) / 256; ++j) {
                int flat = t + 256 * j;
                int c = flat / KQ8, kq = flat % KQ8;
                uint4 v = *(const uint4*)&Wt[(size_t)(col0 + c) * K + 8 * kq];
                *(uint4*)&Bt[c * LDK + 8 * kq] = v;
            }
        }
        __syncthreads();

        f32x4 acc[4];
#pragma unroll
        for (int nf = 0; nf < 4; ++nf) acc[nf] = (f32x4){0.f, 0.f, 0.f, 0.f};
#pragma unroll
        for (int ki = 0; ki < K / 32; ++ki) {
#pragma unroll
            for (int nf = 0; nf < 4; ++nf) {
                half8 bf = *(const half8*)&Bt[(16 * nf + n16) * LDK + 32 * ki + 8 * quad];
                acc[nf] = __builtin_amdgcn_mfma_f32_16x16x32_f16(af[ki], bf, acc[nf], 0, 0, 0);
            }
        }

        // ---- attention dots for this col tile's head(s) ----
        float dps[HPB][4], dpd[HPB][4];
#pragma unroll
        for (int u = 0; u < HPB; ++u)
#pragma unroll
            for (int r = 0; r < 4; ++r) { dps[u][r] = 0.f; dpd[u][r] = 0.f; }
#pragma unroll
        for (int nf = 0; nf < 4; ++nf) {
            int gc = col0 + 16 * nf + n16;
            float cs = atts[gc], cd = attd[gc];
#pragma unroll
            for (int r = 0; r < 4; ++r) {
                float av = acc[nf][r];
                dps[(16 * nf) / C][r] += av * cs;
                dpd[(16 * nf) / C][r] += av * cd;
            }
        }
#pragma unroll
        for (int u = 0; u < HPB; ++u)
#pragma unroll
            for (int r = 0; r < 4; ++r) {
                float s = dps[u][r], d = dpd[u][r];
#pragma unroll
                for (int off = 1; off < 16; off <<= 1) {
                    s += __shfl_xor(s, off, 64);
                    d += __shfl_xor(d, off, 64);
                }
                dps[u][r] = s; dpd[u][r] = d;
            }
        if (n16 == 0) {
            const int h0 = col0 / C;
#pragma unroll
            for (int r = 0; r < 4; ++r) {
                int row = row0 + 16 * wv + 4 * quad + r;
                if (row < Nr) {
#pragma unroll
                    for (int u = 0; u < HPB; ++u) {
                        as_[row * Hn + h0 + u] = dps[u][r];   // plain store
                        ad_[row * Hn + h0 + u] = dpd[u][r];
                    }
                }
            }
        }

        // ---- store h tile via Ht bounce (stride 72) for dwordx4 stores ----
#pragma unroll
        for (int nf = 0; nf < 4; ++nf)
#pragma unroll
            for (int r = 0; r < 4; ++r)
                Ht[(16 * wv + 4 * quad + r) * 72 + 16 * nf + n16] = (_Float16)acc[nf][r];
        __syncthreads();
#pragma unroll
        for (int j = 0; j < 2; ++j) {
            int chunk = t + 256 * j;  // 64 rows x 8 chunks of 8 f16
            int r = chunk >> 3, cc = chunk & 7;
            int row = row0 + r;
            if (row < Nr) {
                uint4 v = *(const uint4*)&Ht[r * 72 + 8 * cc];
                *(uint4*)&Hout[(size_t)row * M + col0 + 8 * cc] = v;
            }
        }
    }
}

// ---------------------------------------------------------------------------
// CSR build: histogram -> 3-stage scan -> scatter (ssrc stored u16: N < 65536).
// ---------------------------------------------------------------------------
__global__ __launch_bounds__(256) void count_kernel(const int* __restrict__ dst,
                                                    int* __restrict__ deg, int Ecnt) {
    int e = blockIdx.x * 256 + threadIdx.x;
    if (e < Ecnt) atomicAdd(&deg[dst[e]], 1);
}

__global__ __launch_bounds__(256) void scan_partial(const int* __restrict__ deg,
                                                    int* __restrict__ bsum, int n) {
    int i = blockIdx.x * 256 + threadIdx.x;
    int v = (i < n) ? deg[i] : 0;
    int lane = threadIdx.x & 63, wv = threadIdx.x >> 6;
#pragma unroll
    for (int off = 32; off > 0; off >>= 1) v += __shfl_down(v, off, 64);
    __shared__ int wt[4];
    if (lane == 0) wt[wv] = v;
    __syncthreads();
    if (threadIdx.x == 0) bsum[blockIdx.x] = wt[0] + wt[1] + wt[2] + wt[3];
}

__global__ __launch_bounds__(256) void scan_base(int* __restrict__ bsum, int nb,
                                                 int* __restrict__ total_out) {
    int t = threadIdx.x, lane = t & 63, wv = t >> 6;
    int v = (t < nb) ? bsum[t] : 0;
    int x = v;
#pragma unroll
    for (int off = 1; off < 64; off <<= 1) {
        int y = __shfl_up(x, off, 64);
        if (lane >= off) x += y;
    }
    __shared__ int wt[4];
    if (lane == 63) wt[wv] = x;
    __syncthreads();
    int base = 0;
    for (int k = 0; k < wv; ++k) base += wt[k];
    if (t < nb) bsum[t] = base + x - v;      // exclusive prefix
    if (t == 255) *total_out = base + x;     // grand total -> row_off[N]
}

__global__ __launch_bounds__(256) void scan_final(const int* __restrict__ deg,
                                                  const int* __restrict__ bsum,
                                                  int* __restrict__ row_off,
                                                  int* __restrict__ cursor, int n) {
    int i = blockIdx.x * 256 + threadIdx.x;
    int t = threadIdx.x, lane = t & 63, wv = t >> 6;
    int v = (i < n) ? deg[i] : 0;
    int x = v;
#pragma unroll
    for (int off = 1; off < 64; off <<= 1) {
        int y = __shfl_up(x, off, 64);
        if (lane >= off) x += y;
    }
    __shared__ int wt[4];
    if (lane == 63) wt[wv] = x;
    __syncthreads();
    int base = bsum[blockIdx.x];
    for (int k = 0; k < wv; ++k) base += wt[k];
    int ro = base + x - v;
    if (i < n) { row_off[i] = ro; cursor[i] = ro; }
}

__global__ __launch_bounds__(256) void scatter_kernel(const int* __restrict__ src,
                                                      const int* __restrict__ dst,
                                                      int* __restrict__ cursor,
                                                      unsigned short* __restrict__ ssrc,
                                                      int Ecnt) {
    int e = blockIdx.x * 256 + threadIdx.x;
    if (e >= Ecnt) return;
    int p = atomicAdd(&cursor[dst[e]], 1);
    ssrc[p] = (unsigned short)src[e];
}

// ---------------------------------------------------------------------------
// Fused GAT aggregation (R4-proven structure), f16 h, 4 edges/wave
// (16 lanes each), ssrc u16, 1-iteration-ahead operand prefetch.
// In-group lane l covers h-row elements [l*PER,(l+1)*PER), head = l>>2.
// ---------------------------------------------------------------------------
template<int Hn, int C, bool RELU, bool OUT_F16>
__global__ __launch_bounds__(256) void gat_agg_kernel(
        const int* __restrict__ row_off, const unsigned short* __restrict__ ssrc,
        const float* __restrict__ as_, const float* __restrict__ ad_,
        const _Float16* __restrict__ Hm, const float* __restrict__ bias,
        void* __restrict__ outv, int Nr) {
    constexpr int HC = Hn * C;
    constexpr int PER = HC / 16;     // f16 per lane: 16 (L1) / 8 (L2)
    constexpr int NV = PER / 8;      // uint4 loads per lane: 2 / 1
    int node = blockIdx.x * 4 + (threadIdx.x >> 6);
    int lane = threadIdx.x & 63;
    if (node >= Nr) return;          // wave-uniform
    const int g = lane >> 4;
    const int l = lane & 15;
    const int h = l >> 2;
    const float ad_h = ad_[node * Hn + h];

    const int begin = row_off[node], end = row_off[node + 1];
    const int iters = (end - begin + 3) >> 2;   // wave-uniform

    float acc[PER];
#pragma unroll
    for (int t = 0; t < PER; ++t) acc[t] = 0.f;
    float wsum = 0.f;

    int idx = begin + g;
    int s_cur = (idx < end) ? (int)ssrc[idx] : -1;
    int s_nx = (idx + 4 < end) ? (int)ssrc[idx + 4] : -1;
    float a_cur = 0.f;
    uint4 u_cur[NV] = {};
    if (s_cur >= 0) {
        a_cur = as_[s_cur * Hn + h];
        const uint4* hp = (const uint4*)(Hm + (size_t)s_cur * HC + l * PER);
        u_cur[0] = hp[0];
        if constexpr (NV == 2) u_cur[1] = hp[1];
    }

    for (int it = 0; it < iters; ++it) {
        const int s_pf = s_nx;
        s_nx = (idx + 8 < end) ? (int)ssrc[idx + 8] : -1;
        float a_nx = 0.f;
        uint4 u_nx[NV] = {};
        if (s_pf >= 0) {
            a_nx = as_[s_pf * Hn + h];
            const uint4* hp = (const uint4*)(Hm + (size_t)s_pf * HC + l * PER);
            u_nx[0] = hp[0];
            if constexpr (NV == 2) u_nx[1] = hp[1];
        }
        // compute current (inactive tail: w=0, u_cur zeroed -> no-op)
        float logit = a_cur + ad_h;
        logit = (logit > 0.f) ? logit : NEG_SLOPE * logit;
        float w = (s_cur >= 0) ? __expf(logit) : 0.f;
        wsum += w;
#pragma unroll
        for (int v = 0; v < NV; ++v) {
            float2 f;
            f = __half22float2(*(const __half2*)&u_cur[v].x);
            acc[8 * v + 0] += w * f.x; acc[8 * v + 1] += w * f.y;
            f = __half22float2(*(const __half2*)&u_cur[v].y);
            acc[8 * v + 2] += w * f.x; acc[8 * v + 3] += w * f.y;
            f = __half22float2(*(const __half2*)&u_cur[v].z);
            acc[8 * v + 4] += w * f.x; acc[8 * v + 5] += w * f.y;
            f = __half22float2(*(const __half2*)&u_cur[v].w);
            acc[8 * v + 6] += w * f.x; acc[8 * v + 7] += w * f.y;
        }
        s_cur = s_pf; a_cur = a_nx;
#pragma unroll
        for (int v = 0; v < NV; ++v) u_cur[v] = u_nx[v];
        idx += 4;
    }

#pragma unroll
    for (int t = 0; t < PER; ++t) {
        acc[t] += __shfl_xor(acc[t], 16, 64);
        acc[t] += __shfl_xor(acc[t], 32, 64);
    }
    wsum += __shfl_xor(wsum, 16, 64);
    wsum += __shfl_xor(wsum, 32, 64);
    const float inv = 1.f / (wsum + EPS_GAT);    // zero-degree: 0/eps = 0
    float val[PER];
#pragma unroll
    for (int t = 0; t < PER; ++t) {
        float v = acc[t] * inv;
        v += __shfl_xor(v, 4, 64);               // head mean
        v += __shfl_xor(v, 8, 64);
        val[t] = v * (1.0f / Hn);
    }
    if (lane < 4) {
        const int c0 = lane * PER;
#pragma unroll
        for (int t = 0; t < PER; ++t) {
            float v = val[t] + bias[c0 + t];
            if (RELU) v = fmaxf(v, 0.f);
            val[t] = v;
        }
        if constexpr (OUT_F16) {
            _Float16* o = (_Float16*)outv;
            _Float16 tmp[PER];
#pragma unroll
            for (int t = 0; t < PER; ++t) tmp[t] = (_Float16)val[t];
            uint4* d4 = (uint4*)&o[(size_t)node * C + c0];
            d4[0] = *(const uint4*)&tmp[0];
            if constexpr (NV == 2) d4[1] = *(const uint4*)&tmp[8];
        } else {
            float* o = (float*)outv;
#pragma unroll
            for (int t4 = 0; t4 < PER / 4; ++t4)
                *(float4*)&o[(size_t)node * C + c0 + 4 * t4] =
                    make_float4(val[4 * t4 + 0], val[4 * t4 + 1],
                                val[4 * t4 + 2], val[4 * t4 + 3]);
        }
    }
}

// ---------------------------------------------------------------------------
extern "C" void kernel_launch(void* const* d_in, const int* in_sizes, int n_in,
                              void* d_out, int out_size, void* d_ws, size_t ws_size,
                              hipStream_t stream) {
    const float* x    = (const float*)d_in[0];
    const int*   ei   = (const int*)d_in[1];
    const float* W1   = (const float*)d_in[2];
    const float* as1w = (const float*)d_in[3];
    const float* ad1w = (const float*)d_in[4];
    const float* b1   = (const float*)d_in[5];
    const float* W2   = (const float*)d_in[6];
    const float* as2w = (const float*)d_in[7];
    const float* ad2w = (const float*)d_in[8];
    const float* b2   = (const float*)d_in[9];
    float* out = (float*)d_out;

    const int* src = ei;             // edge_index[0]
    const int* dst = ei + N_EDGES;   // edge_index[1]

    char* ws = (char*)d_ws;
    size_t off = 0;
    auto alloc = [&](size_t bytes) -> void* {
        void* p = ws + off;
        off = (off + bytes + 255) & ~(size_t)255;
        return p;
    };
    const int NB = (N_NODES + 255) / 256;   // 196 scan blocks
    int*   deg  = (int*)alloc((size_t)N_NODES * 4);
    float* as1_ = (float*)alloc((size_t)N_NODES * H_HEADS * 4);   // plain-stored
    float* ad1_ = (float*)alloc((size_t)N_NODES * H_HEADS * 4);
    float* as2_ = (float*)alloc((size_t)N_NODES * H_HEADS * 4);
    float* ad2_ = (float*)alloc((size_t)N_NODES * H_HEADS * 4);

    _Float16* h1   = (_Float16*)alloc((size_t)N_NODES * H_HEADS * C1 * 2);  // 25.6 MB
    _Float16* out1 = (_Float16*)alloc((size_t)N_NODES * C1 * 2);            // 6.4 MB
    _Float16* h2   = (_Float16*)alloc((size_t)N_NODES * H_HEADS * C2 * 2);  // 12.8 MB
    _Float16* wt1  = (_Float16*)alloc((size_t)(H_HEADS * C1) * F_IN * 2);   // 64 KB
    _Float16* wt2  = (_Float16*)alloc((size_t)(H_HEADS * C2) * C1 * 2);     // 16 KB
    int*   row_off = (int*)alloc((size_t)(N_NODES + 1) * 4);
    int*   cursor  = (int*)alloc((size_t)N_NODES * 4);
    unsigned short* ssrc = (unsigned short*)alloc((size_t)N_EDGES * 2);     // 1.6 MB
    int*   bsum    = (int*)alloc((size_t)NB * 4);

    // ---- zero deg + W transposes + CSR build ----
    hipMemsetAsync(deg, 0, (size_t)N_NODES * 4, stream);
    wtrans_both_kernel<<<10, 256, 0, stream>>>(W1, wt1, W2, wt2);
    count_kernel<<<(N_EDGES + 255) / 256, 256, 0, stream>>>(dst, deg, N_EDGES);
    scan_partial<<<NB, 256, 0, stream>>>(deg, bsum, N_NODES);
    scan_base<<<1, 256, 0, stream>>>(bsum, NB, &row_off[N_NODES]);
    scan_final<<<NB, 256, 0, stream>>>(deg, bsum, row_off, cursor, N_NODES);
    scatter_kernel<<<(N_EDGES + 255) / 256, 256, 0, stream>>>(src, dst, cursor, ssrc, N_EDGES);

    // ---- layer 1 ----
    gemm_att_kernel<F_IN, H_HEADS * C1, H_HEADS, C1, float>
        <<<(N_NODES + 63) / 64, 256, 0, stream>>>(
            x, wt1, h1, as1w, ad1w, as1_, ad1_, N_NODES);
    gat_agg_kernel<H_HEADS, C1, true, true><<<(N_NODES + 3) / 4, 256, 0, stream>>>(
        row_off, ssrc, as1_, ad1_, h1, b1, (void*)out1, N_NODES);

    // ---- layer 2 ----
    gemm_att_kernel<C1, H_HEADS * C2, H_HEADS, C2, _Float16>
        <<<(N_NODES + 63) / 64, 256, 0, stream>>>(
            out1, wt2, h2, as2w, ad2w, as2_, ad2_, N_NODES);
    gat_agg_kernel<H_HEADS, C2, false, false><<<(N_NODES + 3) / 4, 256, 0, stream>>>(
        row_off, ssrc, as2_, ad2_, h2, b2, (void*)out, N_NODES);
}